// Round 4
// baseline (1781.808 us; speedup 1.0000x reference)
//
#include <hip/hip_runtime.h>
#include <cfloat>

// PointNet / DGCNN: B=64, N=1024, F=5, W=128, K=2, D2=768
// R4: XOR block8-swizzled LDS layouts (stride 128, phys block = (row>>3)^(k>>2))
//     -> all ds_read_b128 16B-aligned, staging scalar stores 2-way (free).
//     R3's pad=133 broke b128 alignment (split reads, VALU addr bloat).
//     gemm A-tile same swizzle; W-tile stride 132 (aligned reads). Pool split
//     into 4 n-chunks + combine. FMA k-order unchanged -> identical picks.

__device__ __forceinline__ void top2_update(float& d1, int& j1, float& d2, int& j2,
                                            float dd, int j) {
  if (dd < d1 || (dd == d1 && j < j1)) { d2 = d1; j2 = j1; d1 = dd; j1 = j; }
  else if (dd < d2 || (dd == d2 && j < j2)) { d2 = dd; j2 = j; }
}

__device__ __forceinline__ void top2_merge_xor(float& d1, int& j1, float& d2, int& j2, int m) {
  float od1 = __shfl_xor(d1, m, 64); int oj1 = __shfl_xor(j1, m, 64);
  float od2 = __shfl_xor(d2, m, 64); int oj2 = __shfl_xor(j2, m, 64);
  bool aw = (d1 < od1) || (d1 == od1 && j1 < oj1);
  float h2d = aw ? d2 : od2;  int h2j = aw ? j2 : oj2;
  float lmd = aw ? od1 : d1;  int lmj = aw ? oj1 : j1;
  float nd1 = aw ? d1 : od1;  int nj1 = aw ? j1 : oj1;
  bool bw = (h2d < lmd) || (h2d == lmd && h2j < lmj);
  d1 = nd1; j1 = nj1;
  d2 = bw ? h2d : lmd; j2 = bw ? h2j : lmj;
}

__device__ __forceinline__ void top2_reduce_wave(float& d1, int& j1, float& d2, int& j2) {
  #pragma unroll
  for (int m = 1; m < 64; m <<= 1) top2_merge_xor(d1, j1, d2, j2, m);
}

// ---------------- KNN on 5-dim x ----------------
__global__ __launch_bounds__(256) void pn_knn5(const float* __restrict__ x,
                                               int* __restrict__ idx) {
  __shared__ float xs[5120];
  int t = threadIdx.x;
  int b = blockIdx.x >> 8;
  int r0 = (blockIdx.x & 255) * 4;
  const float4* xb4 = (const float4*)(x + (size_t)b * 5120);
  #pragma unroll
  for (int s = 0; s < 5; ++s) ((float4*)xs)[t + 256 * s] = xb4[t + 256 * s];
  __syncthreads();
  int wv = t >> 6, lane = t & 63;
  int i = r0 + wv;
  float x0 = xs[i*5+0], x1 = xs[i*5+1], x2 = xs[i*5+2], x3 = xs[i*5+3], x4 = xs[i*5+4];
  float d1 = FLT_MAX, d2 = FLT_MAX; int j1 = 0x7fffffff, j2 = 0x7fffffff;
  for (int tS = 0; tS < 16; ++tS) {
    int j = tS * 64 + lane;
    const float* xj = &xs[j * 5];
    float f0 = xj[0] - x0, f1 = xj[1] - x1, f2 = xj[2] - x2, f3 = xj[3] - x3, f4 = xj[4] - x4;
    float dd = f0*f0 + f1*f1 + f2*f2 + f3*f3 + f4*f4;
    top2_update(d1, j1, d2, j2, dd, j);
  }
  top2_reduce_wave(d1, j1, d2, j2);
  if (lane == 0) {
    int r = b * 1024 + i;
    idx[r*2+0] = j1; idx[r*2+1] = j2;
  }
}

// ---------------- conv1 layer1 ----------------
__global__ __launch_bounds__(256) void pn_conv1_l1(const float* __restrict__ x,
                                                   const int* __restrict__ idx,
                                                   const float* __restrict__ w1,
                                                   const float* __restrict__ b1,
                                                   float* __restrict__ h1) {
  __shared__ float Ws[1280];
  __shared__ float Bs[128];
  for (int s = threadIdx.x; s < 1280; s += 256) Ws[s] = w1[s];
  if (threadIdx.x < 128) Bs[threadIdx.x] = b1[threadIdx.x];
  __syncthreads();
  int c = threadIdx.x & 127, rr = threadIdx.x >> 7;
  #pragma unroll
  for (int s = 0; s < 4; ++s) {
    int r = blockIdx.x * 8 + s * 2 + rr;
    int i = r >> 1, k = r & 1;
    int j = idx[i*2 + k];
    int jrow = ((i >> 10) << 10) + j;
    const float* xi = x + (size_t)i * 5;
    const float* xj = x + (size_t)jrow * 5;
    float acc = Bs[c];
    #pragma unroll
    for (int f = 0; f < 5; ++f) {
      float a = xi[f];
      float d = xj[f] - a;
      acc = fmaf(a, Ws[f*128 + c], acc);
      acc = fmaf(d, Ws[(5+f)*128 + c], acc);
    }
    h1[(size_t)r * 128 + c] = fmaxf(acc, 0.0f);
  }
}

// ---------------- GEMM core: A[128 rows] @ W[128,128] ----------------
// As: swizzled [32][128], phys block8 = (row>>3) ^ (k>>2). Wsb: [32][132].
template<bool RELU, bool PAIRMAX>
__device__ __forceinline__ void gemm128_core(int bid, const float* __restrict__ A,
                                             const float* __restrict__ W,
                                             const float* __restrict__ bias,
                                             float* __restrict__ out) {
  __shared__ __align__(16) float As[4096];
  __shared__ __align__(16) float Wsb[32][132];
  int t = threadIdx.x;
  int rg = t >> 4;
  int cg = t & 15;
  float acc[8][8];
  #pragma unroll
  for (int a = 0; a < 8; ++a)
    #pragma unroll
    for (int b = 0; b < 8; ++b) acc[a][b] = 0.f;
  size_t r0 = (size_t)bid * 128;
  int ra = t >> 1, hf = t & 1;
  int wb = t >> 3, cp = t & 7;
  for (int w0 = 0; w0 < 128; w0 += 32) {
    const float* asrc = A + (r0 + ra) * 128 + w0 + hf * 16;
    #pragma unroll
    for (int q = 0; q < 4; ++q) {
      float4 v = ((const float4*)asrc)[q];
      int base = ((hf << 4) + (q << 2)) * 128 +
                 ((((ra >> 3) ^ ((hf << 2) + q)) << 3) | (ra & 7));
      As[base] = v.x; As[base+128] = v.y; As[base+256] = v.z; As[base+384] = v.w;
    }
    const float* wsrc = W + (size_t)(w0 + wb) * 128 + cp * 16;
    #pragma unroll
    for (int q = 0; q < 4; ++q)
      *(float4*)&Wsb[wb][cp*16 + q*4] = ((const float4*)wsrc)[q];
    __syncthreads();
    #pragma unroll
    for (int k4 = 0; k4 < 8; ++k4) {
      const float* pa = &As[(k4 << 9) + ((rg ^ k4) << 3)];
      #pragma unroll
      for (int kk = 0; kk < 4; ++kk) {
        int w = (k4 << 2) + kk;
        float4 a0 = *(const float4*)(pa + (kk << 7));
        float4 a1 = *(const float4*)(pa + (kk << 7) + 4);
        float4 wv0 = *(const float4*)&Wsb[w][cg*4];
        float4 wv1 = *(const float4*)&Wsb[w][64 + cg*4];
        float av[8] = {a0.x,a0.y,a0.z,a0.w,a1.x,a1.y,a1.z,a1.w};
        float wv[8] = {wv0.x,wv0.y,wv0.z,wv0.w,wv1.x,wv1.y,wv1.z,wv1.w};
        #pragma unroll
        for (int ri = 0; ri < 8; ++ri)
          #pragma unroll
          for (int ci = 0; ci < 8; ++ci)
            acc[ri][ci] = fmaf(av[ri], wv[ci], acc[ri][ci]);
      }
    }
    __syncthreads();
  }
  float blo[4], bhi[4];
  #pragma unroll
  for (int ci = 0; ci < 4; ++ci) {
    blo[ci] = bias ? bias[cg*4 + ci] : 0.f;
    bhi[ci] = bias ? bias[64 + cg*4 + ci] : 0.f;
  }
  if (PAIRMAX) {
    #pragma unroll
    for (int ri = 0; ri < 8; ri += 2) {
      size_t orow = (r0 + rg*8 + ri) >> 1;
      float lo[4], hi[4];
      #pragma unroll
      for (int ci = 0; ci < 4; ++ci) {
        float v0 = acc[ri][ci]   + blo[ci];
        float v1 = acc[ri+1][ci] + blo[ci];
        lo[ci] = fmaxf(fmaxf(v0, v1), 0.f);
        float w0v = acc[ri][ci+4]   + bhi[ci];
        float w1v = acc[ri+1][ci+4] + bhi[ci];
        hi[ci] = fmaxf(fmaxf(w0v, w1v), 0.f);
      }
      *(float4*)&out[orow*128 + cg*4]      = *(float4*)lo;
      *(float4*)&out[orow*128 + 64 + cg*4] = *(float4*)hi;
    }
  } else {
    #pragma unroll
    for (int ri = 0; ri < 8; ++ri) {
      size_t row = r0 + rg*8 + ri;
      float lo[4], hi[4];
      #pragma unroll
      for (int ci = 0; ci < 4; ++ci) {
        float v0 = acc[ri][ci]   + blo[ci];
        float v1 = acc[ri][ci+4] + bhi[ci];
        lo[ci] = RELU ? fmaxf(v0, 0.f) : v0;
        hi[ci] = RELU ? fmaxf(v1, 0.f) : v1;
      }
      *(float4*)&out[row*128 + cg*4]      = *(float4*)lo;
      *(float4*)&out[row*128 + 64 + cg*4] = *(float4*)hi;
    }
  }
}

__global__ __launch_bounds__(256) void pn_gemm128_bias(const float* __restrict__ A,
                                                       const float* __restrict__ W,
                                                       const float* __restrict__ bias,
                                                       float* __restrict__ out) {
  gemm128_core<true, true>(blockIdx.x, A, W, bias, out);
}

__global__ __launch_bounds__(256) void pn_gemm128_uv(const float* __restrict__ A,
                                                     const float* __restrict__ Wb,
                                                     float* __restrict__ U,
                                                     float* __restrict__ V) {
  int which = blockIdx.x >> 9;
  gemm128_core<false, false>(blockIdx.x & 511, A, Wb + (which << 14), nullptr,
                             which ? V : U);
}

// ---------------- row squared norms ----------------
__global__ __launch_bounds__(256) void pn_sqnorm(const float* __restrict__ y,
                                                 float* __restrict__ sq) {
  int r = blockIdx.x * 256 + threadIdx.x;
  const float4* p = (const float4*)(y + (size_t)r * 128);
  float s = 0.f;
  #pragma unroll
  for (int q = 0; q < 32; ++q) {
    float4 v = p[q];
    s += v.x*v.x + v.y*v.y + v.z*v.z + v.w*v.w;
  }
  sq[r] = s;
}

// ---------------- KNN-128 Gram tile: 128 i x 64 j, j-split 16 ----------------
// grid = 64 ev x 16 jh x 8 itile = 8192 blocks. Swizzled LDS, stride 128/64.
__global__ __launch_bounds__(256, 4) void pn_knn128(const float* __restrict__ Y,
                                                    const float* __restrict__ sqn,
                                                    int4* __restrict__ cand) {
  __shared__ __align__(16) float As[4096];   // [32 k][128 i] swizzled
  __shared__ __align__(16) float Bs[2048];   // [32 k][64 j]  swizzled
  int t = threadIdx.x;
  int rg = t >> 4, cg = t & 15;
  int b  = blockIdx.x >> 7;
  int jh = (blockIdx.x >> 3) & 15;
  int it = blockIdx.x & 7;
  int i0 = it * 128, j0 = jh * 64;
  const float* Yb  = Y   + (size_t)b * (1024 * 128);
  const float* sqb = sqn + b * 1024;

  float sqi[8];
  #pragma unroll
  for (int ri = 0; ri < 8; ++ri) sqi[ri] = sqb[i0 + rg*8 + ri];

  float acc[8][4];
  #pragma unroll
  for (int a = 0; a < 8; ++a)
    #pragma unroll
    for (int c = 0; c < 4; ++c) acc[a][c] = 0.f;

  int kq = t & 7, rowA = t >> 3;      // rowA in [0,32)
  float4 pA[4], pB[2];
  #pragma unroll
  for (int q = 0; q < 4; ++q)
    pA[q] = *(const float4*)&Yb[(size_t)(i0 + rowA + 32*q) * 128 + kq*4];
  #pragma unroll
  for (int q = 0; q < 2; ++q)
    pB[q] = *(const float4*)&Yb[(size_t)(j0 + rowA + 32*q) * 128 + kq*4];

  for (int k0c = 0; k0c < 4; ++k0c) {
    __syncthreads();
    #pragma unroll
    for (int q = 0; q < 4; ++q) {
      int row = rowA + 32*q;
      int base = (kq << 9) + ((((row >> 3) ^ kq) << 3) | (row & 7));
      As[base]     = pA[q].x; As[base+128] = pA[q].y;
      As[base+256] = pA[q].z; As[base+384] = pA[q].w;
    }
    #pragma unroll
    for (int q = 0; q < 2; ++q) {
      int row = rowA + 32*q;
      int base = (kq << 8) + ((((row >> 3) ^ kq) << 3) | (row & 7));
      Bs[base]     = pB[q].x; Bs[base+64]  = pB[q].y;
      Bs[base+128] = pB[q].z; Bs[base+192] = pB[q].w;
    }
    __syncthreads();
    if (k0c < 3) {
      int kn = (k0c + 1) * 32;
      #pragma unroll
      for (int q = 0; q < 4; ++q)
        pA[q] = *(const float4*)&Yb[(size_t)(i0 + rowA + 32*q) * 128 + kn + kq*4];
      #pragma unroll
      for (int q = 0; q < 2; ++q)
        pB[q] = *(const float4*)&Yb[(size_t)(j0 + rowA + 32*q) * 128 + kn + kq*4];
    }
    #pragma unroll
    for (int k4 = 0; k4 < 8; ++k4) {
      const float* pa = &As[(k4 << 9) + ((rg ^ k4) << 3)];
      const float* pb = &Bs[(k4 << 8) + ((((cg >> 1) ^ k4) << 3) | ((cg & 1) << 2))];
      #pragma unroll
      for (int kk = 0; kk < 4; ++kk) {
        float4 a0 = *(const float4*)(pa + (kk << 7));
        float4 a1 = *(const float4*)(pa + (kk << 7) + 4);
        float4 b0 = *(const float4*)(pb + (kk << 6));
        float av[8] = {a0.x,a0.y,a0.z,a0.w,a1.x,a1.y,a1.z,a1.w};
        float bv[4] = {b0.x,b0.y,b0.z,b0.w};
        #pragma unroll
        for (int ri = 0; ri < 8; ++ri)
          #pragma unroll
          for (int ci = 0; ci < 4; ++ci)
            acc[ri][ci] = fmaf(av[ri], bv[ci], acc[ri][ci]);
      }
    }
  }

  float4 sqj = *(const float4*)&sqb[j0 + cg*4];
  float sj[4] = {sqj.x, sqj.y, sqj.z, sqj.w};
  #pragma unroll
  for (int ri = 0; ri < 8; ++ri) {
    float d1 = FLT_MAX, d2 = FLT_MAX; int j1 = 0x7fffffff, j2 = 0x7fffffff;
    #pragma unroll
    for (int ci = 0; ci < 4; ++ci) {
      int j = j0 + cg*4 + ci;
      float dd = sqi[ri] + sj[ci] - 2.0f * acc[ri][ci];
      top2_update(d1, j1, d2, j2, dd, j);
    }
    top2_merge_xor(d1, j1, d2, j2, 1);
    top2_merge_xor(d1, j1, d2, j2, 2);
    top2_merge_xor(d1, j1, d2, j2, 4);
    top2_merge_xor(d1, j1, d2, j2, 8);
    if (cg == 0) {
      int row = b * 1024 + i0 + rg*8 + ri;
      cand[(size_t)jh * 65536 + row] =
        make_int4(__float_as_int(d1), __float_as_int(d2), j1, j2);
    }
  }
}

__global__ __launch_bounds__(256) void pn_knn_merge(const int4* __restrict__ cand,
                                                    int nslice,
                                                    int* __restrict__ idx) {
  int r = blockIdx.x * 256 + threadIdx.x;
  float d1 = FLT_MAX, d2 = FLT_MAX; int j1 = 0x7fffffff, j2 = 0x7fffffff;
  for (int s = 0; s < nslice; ++s) {
    int4 c = cand[(size_t)s * 65536 + r];
    top2_update(d1, j1, d2, j2, __int_as_float(c.x), c.z);
    top2_update(d1, j1, d2, j2, __int_as_float(c.y), c.w);
  }
  idx[r*2+0] = j1; idx[r*2+1] = j2;
}

// ---------------- edge epilogue ----------------
__global__ __launch_bounds__(256) void pn_edge_max(const float* __restrict__ U,
                                                   const float* __restrict__ V,
                                                   const int* __restrict__ idx,
                                                   const float* __restrict__ bias,
                                                   float* __restrict__ y) {
  int gid = blockIdx.x * 256 + threadIdx.x;
  int i = gid >> 5, c4 = (gid & 31) << 2;
  int base = (i >> 10) << 10;
  int j0 = idx[i*2+0], j1 = idx[i*2+1];
  float4 u  = *(const float4*)&U[(size_t)i*128 + c4];
  float4 vi = *(const float4*)&V[(size_t)i*128 + c4];
  float4 v0 = *(const float4*)&V[(size_t)(base + j0)*128 + c4];
  float4 v1 = *(const float4*)&V[(size_t)(base + j1)*128 + c4];
  float4 bb = *(const float4*)&bias[c4];
  float4 o;
  o.x = fmaxf(fmaxf(u.x + v0.x - vi.x + bb.x, u.x + v1.x - vi.x + bb.x), 0.f);
  o.y = fmaxf(fmaxf(u.y + v0.y - vi.y + bb.y, u.y + v1.y - vi.y + bb.y), 0.f);
  o.z = fmaxf(fmaxf(u.z + v0.z - vi.z + bb.z, u.z + v1.z - vi.z + bb.z), 0.f);
  o.w = fmaxf(fmaxf(u.w + v0.w - vi.w + bb.w, u.w + v1.w - vi.w + bb.w), 0.f);
  *(float4*)&y[(size_t)i*128 + c4] = o;
}

// ---------------- pooling: 4 n-chunks + combine ----------------
__global__ __launch_bounds__(384) void pn_pool1(const float* __restrict__ y1,
                                                const float* __restrict__ y2,
                                                const float* __restrict__ y3,
                                                float* __restrict__ pp) {
  int b = blockIdx.x >> 2, ch = blockIdx.x & 3, c = threadIdx.x;
  const float* src = (c < 128) ? (y1 + (size_t)b * 131072 + c)
                   : (c < 256) ? (y2 + (size_t)b * 131072 + (c - 128))
                               : (y3 + (size_t)b * 131072 + (c - 256));
  src += (size_t)ch * 256 * 128;
  float s = 0.f, mx = -FLT_MAX;
  for (int n = 0; n < 256; ++n) {
    float v = src[(size_t)n * 128];
    s += v; mx = fmaxf(mx, v);
  }
  pp[(size_t)(b*4 + ch) * 768 + c] = s;
  pp[(size_t)(b*4 + ch) * 768 + 384 + c] = mx;
}

__global__ __launch_bounds__(384) void pn_pool2(const float* __restrict__ pp,
                                                float* __restrict__ g) {
  int b = blockIdx.x, c = threadIdx.x;
  float s = 0.f, mx = -FLT_MAX;
  #pragma unroll
  for (int ch = 0; ch < 4; ++ch) {
    s += pp[(size_t)(b*4 + ch) * 768 + c];
    mx = fmaxf(mx, pp[(size_t)(b*4 + ch) * 768 + 384 + c]);
  }
  g[b*768 + c] = s * (1.0f / 1024.0f);
  g[b*768 + 384 + c] = mx;
}

// ---------------- batchnorm ----------------
__global__ __launch_bounds__(256) void pn_bn(const float* __restrict__ g,
                                             const float* __restrict__ gamma,
                                             const float* __restrict__ beta,
                                             float* __restrict__ out) {
  int c = blockIdx.x * 256 + threadIdx.x;
  float mu = 0.f;
  for (int b = 0; b < 64; ++b) mu += g[b*768 + c];
  mu *= (1.0f / 64.0f);
  float var = 0.f;
  for (int b = 0; b < 64; ++b) { float d = g[b*768 + c] - mu; var += d * d; }
  var *= (1.0f / 64.0f);
  float sc = (1.0f / sqrtf(var + 1e-5f)) * gamma[c];
  float sh = beta[c];
  for (int b = 0; b < 64; ++b) out[b*768 + c] = (g[b*768 + c] - mu) * sc + sh;
}

// ---------------- dense 768->768 (+leaky) ----------------
__global__ __launch_bounds__(256) void pn_dense(const float* __restrict__ h,
                                                const float* __restrict__ W,
                                                const float* __restrict__ bias,
                                                float* __restrict__ out) {
  int b = blockIdx.x / 3;
  int c = (blockIdx.x % 3) * 256 + threadIdx.x;
  const float* hb = h + (size_t)b * 768;
  float acc = bias[c];
  for (int w = 0; w < 768; ++w) acc = fmaf(hb[w], W[(size_t)w*768 + c], acc);
  acc = acc > 0.f ? acc : 0.01f * acc;
  out[b*768 + c] = acc;
}

// ---------------- final 768->1 ----------------
__global__ __launch_bounds__(256) void pn_out(const float* __restrict__ h,
                                              const float* __restrict__ ow,
                                              const float* __restrict__ ob,
                                              float* __restrict__ out) {
  int wid = blockIdx.x * 4 + (threadIdx.x >> 6);
  int lane = threadIdx.x & 63;
  const float* hb = h + (size_t)wid * 768;
  float s = 0.f;
  #pragma unroll
  for (int q = 0; q < 12; ++q) {
    int w = q * 64 + lane;
    s = fmaf(hb[w], ow[w], s);
  }
  #pragma unroll
  for (int m = 1; m < 64; m <<= 1) s += __shfl_xor(s, m, 64);
  if (lane == 0) out[wid] = s + ob[0];
}

extern "C" void kernel_launch(void* const* d_in, const int* in_sizes, int n_in,
                              void* d_out, int out_size, void* d_ws, size_t ws_size,
                              hipStream_t stream) {
  (void)in_sizes; (void)n_in; (void)out_size; (void)ws_size;
  const float* x     = (const float*)d_in[0];
  const float* p1w1  = (const float*)d_in[1];
  const float* p1b1  = (const float*)d_in[2];
  const float* p1w2  = (const float*)d_in[3];
  const float* p1b2  = (const float*)d_in[4];
  const float* cw    = (const float*)d_in[5];
  const float* cb    = (const float*)d_in[6];
  const float* bng   = (const float*)d_in[7];
  const float* bnb   = (const float*)d_in[8];
  const float* linw  = (const float*)d_in[9];
  const float* linb  = (const float*)d_in[10];
  const float* outw  = (const float*)d_in[11];
  const float* outb  = (const float*)d_in[12];
  float* outp = (float*)d_out;

  float* ws = (float*)d_ws;
  const size_t YSZ = (size_t)65536 * 128;
  float* y1 = ws;
  float* y2 = y1 + YSZ;
  float* y3 = y2 + YSZ;
  float* U  = y3 + YSZ;
  float* V  = U + YSZ;
  float* h1 = U;                     // conv1 scratch, dead after first gemm
  int4*  cand = (int4*)V;            // knn scratch (16 MB), dead before V write
  float* sq = V + YSZ;
  int*   idxb = (int*)(sq + 65536);
  float* g  = (float*)(idxb + 131072);
  float* ha = g + 49152;
  float* hb = ha + 49152;
  float* pp = hb + 49152;            // pool partials: 256*768 floats

  // --- conv1 ---
  pn_knn5<<<16384, 256, 0, stream>>>(x, idxb);
  pn_conv1_l1<<<16384, 256, 0, stream>>>(x, idxb, p1w1, p1b1, h1);
  pn_gemm128_bias<<<1024, 256, 0, stream>>>(h1, p1w2, p1b2, y1);
  // --- conv2 ---
  pn_sqnorm<<<256, 256, 0, stream>>>(y1, sq);
  pn_knn128<<<8192, 256, 0, stream>>>(y1, sq, cand);
  pn_knn_merge<<<256, 256, 0, stream>>>(cand, 16, idxb);
  pn_gemm128_uv<<<1024, 256, 0, stream>>>(y1, cw, U, V);
  pn_edge_max<<<8192, 256, 0, stream>>>(U, V, idxb, cb, y2);
  // --- conv3 ---
  pn_sqnorm<<<256, 256, 0, stream>>>(y2, sq);
  pn_knn128<<<8192, 256, 0, stream>>>(y2, sq, cand);
  pn_knn_merge<<<256, 256, 0, stream>>>(cand, 16, idxb);
  pn_gemm128_uv<<<1024, 256, 0, stream>>>(y2, cw + 32768, U, V);
  pn_edge_max<<<8192, 256, 0, stream>>>(U, V, idxb, cb + 128, y3);
  // --- head ---
  pn_pool1<<<256, 384, 0, stream>>>(y1, y2, y3, pp);
  pn_pool2<<<64, 384, 0, stream>>>(pp, g);
  pn_bn<<<3, 256, 0, stream>>>(g, bng, bnb, ha);
  pn_dense<<<192, 256, 0, stream>>>(ha, linw + 0*589824, linb + 0*768, hb);
  pn_dense<<<192, 256, 0, stream>>>(hb, linw + 1*589824, linb + 1*768, ha);
  pn_dense<<<192, 256, 0, stream>>>(ha, linw + 2*589824, linb + 2*768, hb);
  pn_dense<<<192, 256, 0, stream>>>(hb, linw + 3*589824, linb + 3*768, ha);
  pn_dense<<<192, 256, 0, stream>>>(ha, linw + 4*589824, linb + 4*768, hb);
  pn_out<<<16, 256, 0, stream>>>(hb, outw, outb, outp);
}

// Round 5
// 1556.633 us; speedup vs baseline: 1.1447x; 1.1447x over previous
//
#include <hip/hip_runtime.h>
#include <cfloat>

// PointNet / DGCNN: B=64, N=1024, F=5, W=128, K=2, D2=768
// R5: R4's swizzled-LDS knn128 WITHOUT the launch_bounds(256,4) min-occupancy
//     clamp. R3/R4 PMC showed the clamp forced VGPR=64 -> scratch spill
//     (WRITE_SIZE 524 MB/dispatch in R4). Compiler now free to use ~128 VGPR,
//     no spill. Everything else unchanged from R4.

__device__ __forceinline__ void top2_update(float& d1, int& j1, float& d2, int& j2,
                                            float dd, int j) {
  if (dd < d1 || (dd == d1 && j < j1)) { d2 = d1; j2 = j1; d1 = dd; j1 = j; }
  else if (dd < d2 || (dd == d2 && j < j2)) { d2 = dd; j2 = j; }
}

__device__ __forceinline__ void top2_merge_xor(float& d1, int& j1, float& d2, int& j2, int m) {
  float od1 = __shfl_xor(d1, m, 64); int oj1 = __shfl_xor(j1, m, 64);
  float od2 = __shfl_xor(d2, m, 64); int oj2 = __shfl_xor(j2, m, 64);
  bool aw = (d1 < od1) || (d1 == od1 && j1 < oj1);
  float h2d = aw ? d2 : od2;  int h2j = aw ? j2 : oj2;
  float lmd = aw ? od1 : d1;  int lmj = aw ? oj1 : j1;
  float nd1 = aw ? d1 : od1;  int nj1 = aw ? j1 : oj1;
  bool bw = (h2d < lmd) || (h2d == lmd && h2j < lmj);
  d1 = nd1; j1 = nj1;
  d2 = bw ? h2d : lmd; j2 = bw ? h2j : lmj;
}

__device__ __forceinline__ void top2_reduce_wave(float& d1, int& j1, float& d2, int& j2) {
  #pragma unroll
  for (int m = 1; m < 64; m <<= 1) top2_merge_xor(d1, j1, d2, j2, m);
}

// ---------------- KNN on 5-dim x ----------------
__global__ __launch_bounds__(256) void pn_knn5(const float* __restrict__ x,
                                               int* __restrict__ idx) {
  __shared__ float xs[5120];
  int t = threadIdx.x;
  int b = blockIdx.x >> 8;
  int r0 = (blockIdx.x & 255) * 4;
  const float4* xb4 = (const float4*)(x + (size_t)b * 5120);
  #pragma unroll
  for (int s = 0; s < 5; ++s) ((float4*)xs)[t + 256 * s] = xb4[t + 256 * s];
  __syncthreads();
  int wv = t >> 6, lane = t & 63;
  int i = r0 + wv;
  float x0 = xs[i*5+0], x1 = xs[i*5+1], x2 = xs[i*5+2], x3 = xs[i*5+3], x4 = xs[i*5+4];
  float d1 = FLT_MAX, d2 = FLT_MAX; int j1 = 0x7fffffff, j2 = 0x7fffffff;
  for (int tS = 0; tS < 16; ++tS) {
    int j = tS * 64 + lane;
    const float* xj = &xs[j * 5];
    float f0 = xj[0] - x0, f1 = xj[1] - x1, f2 = xj[2] - x2, f3 = xj[3] - x3, f4 = xj[4] - x4;
    float dd = f0*f0 + f1*f1 + f2*f2 + f3*f3 + f4*f4;
    top2_update(d1, j1, d2, j2, dd, j);
  }
  top2_reduce_wave(d1, j1, d2, j2);
  if (lane == 0) {
    int r = b * 1024 + i;
    idx[r*2+0] = j1; idx[r*2+1] = j2;
  }
}

// ---------------- conv1 layer1 ----------------
__global__ __launch_bounds__(256) void pn_conv1_l1(const float* __restrict__ x,
                                                   const int* __restrict__ idx,
                                                   const float* __restrict__ w1,
                                                   const float* __restrict__ b1,
                                                   float* __restrict__ h1) {
  __shared__ float Ws[1280];
  __shared__ float Bs[128];
  for (int s = threadIdx.x; s < 1280; s += 256) Ws[s] = w1[s];
  if (threadIdx.x < 128) Bs[threadIdx.x] = b1[threadIdx.x];
  __syncthreads();
  int c = threadIdx.x & 127, rr = threadIdx.x >> 7;
  #pragma unroll
  for (int s = 0; s < 4; ++s) {
    int r = blockIdx.x * 8 + s * 2 + rr;
    int i = r >> 1, k = r & 1;
    int j = idx[i*2 + k];
    int jrow = ((i >> 10) << 10) + j;
    const float* xi = x + (size_t)i * 5;
    const float* xj = x + (size_t)jrow * 5;
    float acc = Bs[c];
    #pragma unroll
    for (int f = 0; f < 5; ++f) {
      float a = xi[f];
      float d = xj[f] - a;
      acc = fmaf(a, Ws[f*128 + c], acc);
      acc = fmaf(d, Ws[(5+f)*128 + c], acc);
    }
    h1[(size_t)r * 128 + c] = fmaxf(acc, 0.0f);
  }
}

// ---------------- GEMM core: A[128 rows] @ W[128,128] ----------------
// As: swizzled [32][128], phys block8 = (row>>3) ^ (k>>2). Wsb: [32][132].
template<bool RELU, bool PAIRMAX>
__device__ __forceinline__ void gemm128_core(int bid, const float* __restrict__ A,
                                             const float* __restrict__ W,
                                             const float* __restrict__ bias,
                                             float* __restrict__ out) {
  __shared__ __align__(16) float As[4096];
  __shared__ __align__(16) float Wsb[32][132];
  int t = threadIdx.x;
  int rg = t >> 4;
  int cg = t & 15;
  float acc[8][8];
  #pragma unroll
  for (int a = 0; a < 8; ++a)
    #pragma unroll
    for (int b = 0; b < 8; ++b) acc[a][b] = 0.f;
  size_t r0 = (size_t)bid * 128;
  int ra = t >> 1, hf = t & 1;
  int wb = t >> 3, cp = t & 7;
  for (int w0 = 0; w0 < 128; w0 += 32) {
    const float* asrc = A + (r0 + ra) * 128 + w0 + hf * 16;
    #pragma unroll
    for (int q = 0; q < 4; ++q) {
      float4 v = ((const float4*)asrc)[q];
      int base = ((hf << 4) + (q << 2)) * 128 +
                 ((((ra >> 3) ^ ((hf << 2) + q)) << 3) | (ra & 7));
      As[base] = v.x; As[base+128] = v.y; As[base+256] = v.z; As[base+384] = v.w;
    }
    const float* wsrc = W + (size_t)(w0 + wb) * 128 + cp * 16;
    #pragma unroll
    for (int q = 0; q < 4; ++q)
      *(float4*)&Wsb[wb][cp*16 + q*4] = ((const float4*)wsrc)[q];
    __syncthreads();
    #pragma unroll
    for (int k4 = 0; k4 < 8; ++k4) {
      const float* pa = &As[(k4 << 9) + ((rg ^ k4) << 3)];
      #pragma unroll
      for (int kk = 0; kk < 4; ++kk) {
        int w = (k4 << 2) + kk;
        float4 a0 = *(const float4*)(pa + (kk << 7));
        float4 a1 = *(const float4*)(pa + (kk << 7) + 4);
        float4 wv0 = *(const float4*)&Wsb[w][cg*4];
        float4 wv1 = *(const float4*)&Wsb[w][64 + cg*4];
        float av[8] = {a0.x,a0.y,a0.z,a0.w,a1.x,a1.y,a1.z,a1.w};
        float wv[8] = {wv0.x,wv0.y,wv0.z,wv0.w,wv1.x,wv1.y,wv1.z,wv1.w};
        #pragma unroll
        for (int ri = 0; ri < 8; ++ri)
          #pragma unroll
          for (int ci = 0; ci < 8; ++ci)
            acc[ri][ci] = fmaf(av[ri], wv[ci], acc[ri][ci]);
      }
    }
    __syncthreads();
  }
  float blo[4], bhi[4];
  #pragma unroll
  for (int ci = 0; ci < 4; ++ci) {
    blo[ci] = bias ? bias[cg*4 + ci] : 0.f;
    bhi[ci] = bias ? bias[64 + cg*4 + ci] : 0.f;
  }
  if (PAIRMAX) {
    #pragma unroll
    for (int ri = 0; ri < 8; ri += 2) {
      size_t orow = (r0 + rg*8 + ri) >> 1;
      float lo[4], hi[4];
      #pragma unroll
      for (int ci = 0; ci < 4; ++ci) {
        float v0 = acc[ri][ci]   + blo[ci];
        float v1 = acc[ri+1][ci] + blo[ci];
        lo[ci] = fmaxf(fmaxf(v0, v1), 0.f);
        float w0v = acc[ri][ci+4]   + bhi[ci];
        float w1v = acc[ri+1][ci+4] + bhi[ci];
        hi[ci] = fmaxf(fmaxf(w0v, w1v), 0.f);
      }
      *(float4*)&out[orow*128 + cg*4]      = *(float4*)lo;
      *(float4*)&out[orow*128 + 64 + cg*4] = *(float4*)hi;
    }
  } else {
    #pragma unroll
    for (int ri = 0; ri < 8; ++ri) {
      size_t row = r0 + rg*8 + ri;
      float lo[4], hi[4];
      #pragma unroll
      for (int ci = 0; ci < 4; ++ci) {
        float v0 = acc[ri][ci]   + blo[ci];
        float v1 = acc[ri][ci+4] + bhi[ci];
        lo[ci] = RELU ? fmaxf(v0, 0.f) : v0;
        hi[ci] = RELU ? fmaxf(v1, 0.f) : v1;
      }
      *(float4*)&out[row*128 + cg*4]      = *(float4*)lo;
      *(float4*)&out[row*128 + 64 + cg*4] = *(float4*)hi;
    }
  }
}

__global__ __launch_bounds__(256) void pn_gemm128_bias(const float* __restrict__ A,
                                                       const float* __restrict__ W,
                                                       const float* __restrict__ bias,
                                                       float* __restrict__ out) {
  gemm128_core<true, true>(blockIdx.x, A, W, bias, out);
}

__global__ __launch_bounds__(256) void pn_gemm128_uv(const float* __restrict__ A,
                                                     const float* __restrict__ Wb,
                                                     float* __restrict__ U,
                                                     float* __restrict__ V) {
  int which = blockIdx.x >> 9;
  gemm128_core<false, false>(blockIdx.x & 511, A, Wb + (which << 14), nullptr,
                             which ? V : U);
}

// ---------------- row squared norms ----------------
__global__ __launch_bounds__(256) void pn_sqnorm(const float* __restrict__ y,
                                                 float* __restrict__ sq) {
  int r = blockIdx.x * 256 + threadIdx.x;
  const float4* p = (const float4*)(y + (size_t)r * 128);
  float s = 0.f;
  #pragma unroll
  for (int q = 0; q < 32; ++q) {
    float4 v = p[q];
    s += v.x*v.x + v.y*v.y + v.z*v.z + v.w*v.w;
  }
  sq[r] = s;
}

// ---------------- KNN-128 Gram tile: 128 i x 64 j, j-split 16 ----------------
// grid = 64 ev x 16 jh x 8 itile = 8192 blocks. Swizzled LDS, stride 128/64.
// NOTE: no min-occupancy bound — (256,4) clamped VGPR to 64 and spilled.
__global__ __launch_bounds__(256) void pn_knn128(const float* __restrict__ Y,
                                                 const float* __restrict__ sqn,
                                                 int4* __restrict__ cand) {
  __shared__ __align__(16) float As[4096];   // [32 k][128 i] swizzled
  __shared__ __align__(16) float Bs[2048];   // [32 k][64 j]  swizzled
  int t = threadIdx.x;
  int rg = t >> 4, cg = t & 15;
  int b  = blockIdx.x >> 7;
  int jh = (blockIdx.x >> 3) & 15;
  int it = blockIdx.x & 7;
  int i0 = it * 128, j0 = jh * 64;
  const float* Yb  = Y   + (size_t)b * (1024 * 128);
  const float* sqb = sqn + b * 1024;

  float sqi[8];
  #pragma unroll
  for (int ri = 0; ri < 8; ++ri) sqi[ri] = sqb[i0 + rg*8 + ri];

  float acc[8][4];
  #pragma unroll
  for (int a = 0; a < 8; ++a)
    #pragma unroll
    for (int c = 0; c < 4; ++c) acc[a][c] = 0.f;

  int kq = t & 7, rowA = t >> 3;      // rowA in [0,32)
  float4 pA[4], pB[2];
  #pragma unroll
  for (int q = 0; q < 4; ++q)
    pA[q] = *(const float4*)&Yb[(size_t)(i0 + rowA + 32*q) * 128 + kq*4];
  #pragma unroll
  for (int q = 0; q < 2; ++q)
    pB[q] = *(const float4*)&Yb[(size_t)(j0 + rowA + 32*q) * 128 + kq*4];

  for (int k0c = 0; k0c < 4; ++k0c) {
    __syncthreads();
    #pragma unroll
    for (int q = 0; q < 4; ++q) {
      int row = rowA + 32*q;
      int base = (kq << 9) + ((((row >> 3) ^ kq) << 3) | (row & 7));
      As[base]     = pA[q].x; As[base+128] = pA[q].y;
      As[base+256] = pA[q].z; As[base+384] = pA[q].w;
    }
    #pragma unroll
    for (int q = 0; q < 2; ++q) {
      int row = rowA + 32*q;
      int base = (kq << 8) + ((((row >> 3) ^ kq) << 3) | (row & 7));
      Bs[base]     = pB[q].x; Bs[base+64]  = pB[q].y;
      Bs[base+128] = pB[q].z; Bs[base+192] = pB[q].w;
    }
    __syncthreads();
    if (k0c < 3) {
      int kn = (k0c + 1) * 32;
      #pragma unroll
      for (int q = 0; q < 4; ++q)
        pA[q] = *(const float4*)&Yb[(size_t)(i0 + rowA + 32*q) * 128 + kn + kq*4];
      #pragma unroll
      for (int q = 0; q < 2; ++q)
        pB[q] = *(const float4*)&Yb[(size_t)(j0 + rowA + 32*q) * 128 + kn + kq*4];
    }
    #pragma unroll
    for (int k4 = 0; k4 < 8; ++k4) {
      const float* pa = &As[(k4 << 9) + ((rg ^ k4) << 3)];
      const float* pb = &Bs[(k4 << 8) + ((((cg >> 1) ^ k4) << 3) | ((cg & 1) << 2))];
      #pragma unroll
      for (int kk = 0; kk < 4; ++kk) {
        float4 a0 = *(const float4*)(pa + (kk << 7));
        float4 a1 = *(const float4*)(pa + (kk << 7) + 4);
        float4 b0 = *(const float4*)(pb + (kk << 6));
        float av[8] = {a0.x,a0.y,a0.z,a0.w,a1.x,a1.y,a1.z,a1.w};
        float bv[4] = {b0.x,b0.y,b0.z,b0.w};
        #pragma unroll
        for (int ri = 0; ri < 8; ++ri)
          #pragma unroll
          for (int ci = 0; ci < 4; ++ci)
            acc[ri][ci] = fmaf(av[ri], bv[ci], acc[ri][ci]);
      }
    }
  }

  float4 sqj = *(const float4*)&sqb[j0 + cg*4];
  float sj[4] = {sqj.x, sqj.y, sqj.z, sqj.w};
  #pragma unroll
  for (int ri = 0; ri < 8; ++ri) {
    float d1 = FLT_MAX, d2 = FLT_MAX; int j1 = 0x7fffffff, j2 = 0x7fffffff;
    #pragma unroll
    for (int ci = 0; ci < 4; ++ci) {
      int j = j0 + cg*4 + ci;
      float dd = sqi[ri] + sj[ci] - 2.0f * acc[ri][ci];
      top2_update(d1, j1, d2, j2, dd, j);
    }
    top2_merge_xor(d1, j1, d2, j2, 1);
    top2_merge_xor(d1, j1, d2, j2, 2);
    top2_merge_xor(d1, j1, d2, j2, 4);
    top2_merge_xor(d1, j1, d2, j2, 8);
    if (cg == 0) {
      int row = b * 1024 + i0 + rg*8 + ri;
      cand[(size_t)jh * 65536 + row] =
        make_int4(__float_as_int(d1), __float_as_int(d2), j1, j2);
    }
  }
}

__global__ __launch_bounds__(256) void pn_knn_merge(const int4* __restrict__ cand,
                                                    int nslice,
                                                    int* __restrict__ idx) {
  int r = blockIdx.x * 256 + threadIdx.x;
  float d1 = FLT_MAX, d2 = FLT_MAX; int j1 = 0x7fffffff, j2 = 0x7fffffff;
  for (int s = 0; s < nslice; ++s) {
    int4 c = cand[(size_t)s * 65536 + r];
    top2_update(d1, j1, d2, j2, __int_as_float(c.x), c.z);
    top2_update(d1, j1, d2, j2, __int_as_float(c.y), c.w);
  }
  idx[r*2+0] = j1; idx[r*2+1] = j2;
}

// ---------------- edge epilogue ----------------
__global__ __launch_bounds__(256) void pn_edge_max(const float* __restrict__ U,
                                                   const float* __restrict__ V,
                                                   const int* __restrict__ idx,
                                                   const float* __restrict__ bias,
                                                   float* __restrict__ y) {
  int gid = blockIdx.x * 256 + threadIdx.x;
  int i = gid >> 5, c4 = (gid & 31) << 2;
  int base = (i >> 10) << 10;
  int j0 = idx[i*2+0], j1 = idx[i*2+1];
  float4 u  = *(const float4*)&U[(size_t)i*128 + c4];
  float4 vi = *(const float4*)&V[(size_t)i*128 + c4];
  float4 v0 = *(const float4*)&V[(size_t)(base + j0)*128 + c4];
  float4 v1 = *(const float4*)&V[(size_t)(base + j1)*128 + c4];
  float4 bb = *(const float4*)&bias[c4];
  float4 o;
  o.x = fmaxf(fmaxf(u.x + v0.x - vi.x + bb.x, u.x + v1.x - vi.x + bb.x), 0.f);
  o.y = fmaxf(fmaxf(u.y + v0.y - vi.y + bb.y, u.y + v1.y - vi.y + bb.y), 0.f);
  o.z = fmaxf(fmaxf(u.z + v0.z - vi.z + bb.z, u.z + v1.z - vi.z + bb.z), 0.f);
  o.w = fmaxf(fmaxf(u.w + v0.w - vi.w + bb.w, u.w + v1.w - vi.w + bb.w), 0.f);
  *(float4*)&y[(size_t)i*128 + c4] = o;
}

// ---------------- pooling: 4 n-chunks + combine ----------------
__global__ __launch_bounds__(384) void pn_pool1(const float* __restrict__ y1,
                                                const float* __restrict__ y2,
                                                const float* __restrict__ y3,
                                                float* __restrict__ pp) {
  int b = blockIdx.x >> 2, ch = blockIdx.x & 3, c = threadIdx.x;
  const float* src = (c < 128) ? (y1 + (size_t)b * 131072 + c)
                   : (c < 256) ? (y2 + (size_t)b * 131072 + (c - 128))
                               : (y3 + (size_t)b * 131072 + (c - 256));
  src += (size_t)ch * 256 * 128;
  float s = 0.f, mx = -FLT_MAX;
  for (int n = 0; n < 256; ++n) {
    float v = src[(size_t)n * 128];
    s += v; mx = fmaxf(mx, v);
  }
  pp[(size_t)(b*4 + ch) * 768 + c] = s;
  pp[(size_t)(b*4 + ch) * 768 + 384 + c] = mx;
}

__global__ __launch_bounds__(384) void pn_pool2(const float* __restrict__ pp,
                                                float* __restrict__ g) {
  int b = blockIdx.x, c = threadIdx.x;
  float s = 0.f, mx = -FLT_MAX;
  #pragma unroll
  for (int ch = 0; ch < 4; ++ch) {
    s += pp[(size_t)(b*4 + ch) * 768 + c];
    mx = fmaxf(mx, pp[(size_t)(b*4 + ch) * 768 + 384 + c]);
  }
  g[b*768 + c] = s * (1.0f / 1024.0f);
  g[b*768 + 384 + c] = mx;
}

// ---------------- batchnorm ----------------
__global__ __launch_bounds__(256) void pn_bn(const float* __restrict__ g,
                                             const float* __restrict__ gamma,
                                             const float* __restrict__ beta,
                                             float* __restrict__ out) {
  int c = blockIdx.x * 256 + threadIdx.x;
  float mu = 0.f;
  for (int b = 0; b < 64; ++b) mu += g[b*768 + c];
  mu *= (1.0f / 64.0f);
  float var = 0.f;
  for (int b = 0; b < 64; ++b) { float d = g[b*768 + c] - mu; var += d * d; }
  var *= (1.0f / 64.0f);
  float sc = (1.0f / sqrtf(var + 1e-5f)) * gamma[c];
  float sh = beta[c];
  for (int b = 0; b < 64; ++b) out[b*768 + c] = (g[b*768 + c] - mu) * sc + sh;
}

// ---------------- dense 768->768 (+leaky) ----------------
__global__ __launch_bounds__(256) void pn_dense(const float* __restrict__ h,
                                                const float* __restrict__ W,
                                                const float* __restrict__ bias,
                                                float* __restrict__ out) {
  int b = blockIdx.x / 3;
  int c = (blockIdx.x % 3) * 256 + threadIdx.x;
  const float* hb = h + (size_t)b * 768;
  float acc = bias[c];
  for (int w = 0; w < 768; ++w) acc = fmaf(hb[w], W[(size_t)w*768 + c], acc);
  acc = acc > 0.f ? acc : 0.01f * acc;
  out[b*768 + c] = acc;
}

// ---------------- final 768->1 ----------------
__global__ __launch_bounds__(256) void pn_out(const float* __restrict__ h,
                                              const float* __restrict__ ow,
                                              const float* __restrict__ ob,
                                              float* __restrict__ out) {
  int wid = blockIdx.x * 4 + (threadIdx.x >> 6);
  int lane = threadIdx.x & 63;
  const float* hb = h + (size_t)wid * 768;
  float s = 0.f;
  #pragma unroll
  for (int q = 0; q < 12; ++q) {
    int w = q * 64 + lane;
    s = fmaf(hb[w], ow[w], s);
  }
  #pragma unroll
  for (int m = 1; m < 64; m <<= 1) s += __shfl_xor(s, m, 64);
  if (lane == 0) out[wid] = s + ob[0];
}

extern "C" void kernel_launch(void* const* d_in, const int* in_sizes, int n_in,
                              void* d_out, int out_size, void* d_ws, size_t ws_size,
                              hipStream_t stream) {
  (void)in_sizes; (void)n_in; (void)out_size; (void)ws_size;
  const float* x     = (const float*)d_in[0];
  const float* p1w1  = (const float*)d_in[1];
  const float* p1b1  = (const float*)d_in[2];
  const float* p1w2  = (const float*)d_in[3];
  const float* p1b2  = (const float*)d_in[4];
  const float* cw    = (const float*)d_in[5];
  const float* cb    = (const float*)d_in[6];
  const float* bng   = (const float*)d_in[7];
  const float* bnb   = (const float*)d_in[8];
  const float* linw  = (const float*)d_in[9];
  const float* linb  = (const float*)d_in[10];
  const float* outw  = (const float*)d_in[11];
  const float* outb  = (const float*)d_in[12];
  float* outp = (float*)d_out;

  float* ws = (float*)d_ws;
  const size_t YSZ = (size_t)65536 * 128;
  float* y1 = ws;
  float* y2 = y1 + YSZ;
  float* y3 = y2 + YSZ;
  float* U  = y3 + YSZ;
  float* V  = U + YSZ;
  float* h1 = U;                     // conv1 scratch, dead after first gemm
  int4*  cand = (int4*)V;            // knn scratch (16 MB), dead before V write
  float* sq = V + YSZ;
  int*   idxb = (int*)(sq + 65536);
  float* g  = (float*)(idxb + 131072);
  float* ha = g + 49152;
  float* hb = ha + 49152;
  float* pp = hb + 49152;            // pool partials: 256*768 floats

  // --- conv1 ---
  pn_knn5<<<16384, 256, 0, stream>>>(x, idxb);
  pn_conv1_l1<<<16384, 256, 0, stream>>>(x, idxb, p1w1, p1b1, h1);
  pn_gemm128_bias<<<1024, 256, 0, stream>>>(h1, p1w2, p1b2, y1);
  // --- conv2 ---
  pn_sqnorm<<<256, 256, 0, stream>>>(y1, sq);
  pn_knn128<<<8192, 256, 0, stream>>>(y1, sq, cand);
  pn_knn_merge<<<256, 256, 0, stream>>>(cand, 16, idxb);
  pn_gemm128_uv<<<1024, 256, 0, stream>>>(y1, cw, U, V);
  pn_edge_max<<<8192, 256, 0, stream>>>(U, V, idxb, cb, y2);
  // --- conv3 ---
  pn_sqnorm<<<256, 256, 0, stream>>>(y2, sq);
  pn_knn128<<<8192, 256, 0, stream>>>(y2, sq, cand);
  pn_knn_merge<<<256, 256, 0, stream>>>(cand, 16, idxb);
  pn_gemm128_uv<<<1024, 256, 0, stream>>>(y2, cw + 32768, U, V);
  pn_edge_max<<<8192, 256, 0, stream>>>(U, V, idxb, cb + 128, y3);
  // --- head ---
  pn_pool1<<<256, 384, 0, stream>>>(y1, y2, y3, pp);
  pn_pool2<<<64, 384, 0, stream>>>(pp, g);
  pn_bn<<<3, 256, 0, stream>>>(g, bng, bnb, ha);
  pn_dense<<<192, 256, 0, stream>>>(ha, linw + 0*589824, linb + 0*768, hb);
  pn_dense<<<192, 256, 0, stream>>>(hb, linw + 1*589824, linb + 1*768, ha);
  pn_dense<<<192, 256, 0, stream>>>(ha, linw + 2*589824, linb + 2*768, hb);
  pn_dense<<<192, 256, 0, stream>>>(hb, linw + 3*589824, linb + 3*768, ha);
  pn_dense<<<192, 256, 0, stream>>>(ha, linw + 4*589824, linb + 4*768, hb);
  pn_out<<<16, 256, 0, stream>>>(hb, outw, outb, outp);
}